// Round 2
// baseline (2004.854 us; speedup 1.0000x reference)
//
#include <hip/hip_runtime.h>

#define NN 100000
#define EE 1600000
#define HH 128
#define GG 64
#define TOT (EE + NN)

// ---------------- graph prep ----------------

__global__ void init_kernel(int* deg, int* gstart, int* gend) {
    int i = blockIdx.x * blockDim.x + threadIdx.x;
    if (i < NN) deg[i] = 1;               // self-loop
    if (i < GG) { gstart[i] = NN; gend[i] = 0; }
}

__global__ void count_kernel(const int* __restrict__ ei, int* deg) {
    int e = blockIdx.x * blockDim.x + threadIdx.x;
    if (e < EE) {
        int c = ei[EE + e];
        if (c >= 0 && c < NN) atomicAdd(&deg[c], 1);   // col = target
    }
}

__global__ void dinv_kernel(const int* __restrict__ deg, float* __restrict__ dinv) {
    int i = blockIdx.x * blockDim.x + threadIdx.x;
    if (i < NN) dinv[i] = rsqrtf((float)deg[i]);  // deg >= 1 always
}

// exclusive scan of deg -> col_start (3 phases)
__global__ void scan1_kernel(const int* __restrict__ deg, int* __restrict__ out, int* __restrict__ bsums) {
    __shared__ int sh[256];
    int x = threadIdx.x;
    int i = blockIdx.x * 256 + x;
    int v = (i < NN) ? deg[i] : 0;
    sh[x] = v;
    __syncthreads();
    for (int off = 1; off < 256; off <<= 1) {
        int t = (x >= off) ? sh[x - off] : 0;
        __syncthreads();
        sh[x] += t;
        __syncthreads();
    }
    if (i < NN) out[i] = sh[x] - v;     // block-local exclusive
    if (x == 255) bsums[blockIdx.x] = sh[255];
}

__global__ void scan2_kernel(int* __restrict__ bsums, int nb) {
    __shared__ int sh[512];
    int x = threadIdx.x;
    int v = (x < nb) ? bsums[x] : 0;
    sh[x] = v;
    __syncthreads();
    for (int off = 1; off < 512; off <<= 1) {
        int t = (x >= off) ? sh[x - off] : 0;
        __syncthreads();
        sh[x] += t;
        __syncthreads();
    }
    if (x < nb) bsums[x] = sh[x] - v;   // exclusive
}

__global__ void scan3_kernel(int* __restrict__ col_start, const int* __restrict__ bsums, int* __restrict__ cursor) {
    int i = blockIdx.x * blockDim.x + threadIdx.x;
    if (i < NN) {
        int v = col_start[i] + bsums[i >> 8];
        col_start[i] = v;
        cursor[i] = v;
    } else if (i == NN) {
        col_start[NN] = TOT;
    }
}

__global__ void fill_kernel(const int* __restrict__ ei, const float* __restrict__ dinv,
                            int* cursor, int* __restrict__ srcv, float* __restrict__ wnorm) {
    int e = blockIdx.x * blockDim.x + threadIdx.x;
    int r, c;
    if (e < EE) { r = ei[e]; c = ei[EE + e]; }
    else if (e < TOT) { r = c = e - EE; }
    else return;
    int slot = atomicAdd(&cursor[c], 1);
    if (slot >= 0 && slot < TOT) {       // defensive: never OOB even if inputs are weird
        srcv[slot] = r;
        wnorm[slot] = dinv[r] * dinv[c];
    }
}

// ---------------- per-layer kernels ----------------

// one block (128 threads) per destination node: gather-weighted-sum
__global__ __launch_bounds__(128) void agg_kernel(const float* __restrict__ X,
                                                  const int* __restrict__ col_start,
                                                  const int* __restrict__ srcv,
                                                  const float* __restrict__ wnorm,
                                                  float* __restrict__ A) {
    int node = blockIdx.x;
    int t = threadIdx.x;
    int s0 = col_start[node], s1 = col_start[node + 1];
    __shared__ int sh_src[128];
    __shared__ float sh_w[128];
    float acc = 0.f;
    for (int base = s0; base < s1; base += 128) {
        int cnt = min(128, s1 - base);
        if (t < cnt) { sh_src[t] = srcv[base + t]; sh_w[t] = wnorm[base + t]; }
        __syncthreads();
        for (int j = 0; j < cnt; ++j) {
            acc += sh_w[j] * X[(size_t)sh_src[j] * HH + t];
        }
        __syncthreads();
    }
    A[(size_t)node * HH + t] = acc;
}

__global__ void zero_stats_kernel(float* gsum, float* gsq) {
    int t = threadIdx.x;
    if (t < HH) { gsum[t] = 0.f; gsq[t] = 0.f; }
}

// H = A @ W + b ; accumulate column sum/sumsq for BN
__global__ __launch_bounds__(256) void gemm_kernel(const float* __restrict__ A,
                                                   const float* __restrict__ W,
                                                   const float* __restrict__ bias,
                                                   float* __restrict__ H,
                                                   float* __restrict__ gsum,
                                                   float* __restrict__ gsq) {
    __shared__ float Ash[64][36];     // 36: keeps float4 rows 16B-aligned, breaks pow2 stride
    __shared__ float Wsh[32][HH];
    __shared__ float ssum[HH], ssq[HH];
    int tid = threadIdx.x;
    int ty = tid >> 5, tx = tid & 31;
    int row0 = blockIdx.x * 64;
    if (tid < HH) { ssum[tid] = 0.f; ssq[tid] = 0.f; }

    float acc[8][4];
#pragma unroll
    for (int r = 0; r < 8; ++r)
#pragma unroll
        for (int q = 0; q < 4; ++q) acc[r][q] = 0.f;

    for (int kt = 0; kt < 4; ++kt) {
        int k0 = kt * 32;
        // stage W tile 32x128
        {
            int r = tid >> 3;
            int cg = (tid & 7) * 16;
            const float4* wp = (const float4*)(W + (size_t)(k0 + r) * HH + cg);
            float4 w0 = wp[0], w1 = wp[1], w2 = wp[2], w3 = wp[3];
            *(float4*)&Wsh[r][cg + 0]  = w0;
            *(float4*)&Wsh[r][cg + 4]  = w1;
            *(float4*)&Wsh[r][cg + 8]  = w2;
            *(float4*)&Wsh[r][cg + 12] = w3;
        }
        // stage A tile 64x32
        {
            int r = tid >> 2;
            int q = tid & 3;
            int grow = row0 + r;
            float4 a0 = make_float4(0.f, 0.f, 0.f, 0.f), a1 = a0;
            if (grow < NN) {
                const float4* ap = (const float4*)(A + (size_t)grow * HH + k0 + q * 8);
                a0 = ap[0]; a1 = ap[1];
            }
            *(float4*)&Ash[r][q * 8 + 0] = a0;
            *(float4*)&Ash[r][q * 8 + 4] = a1;
        }
        __syncthreads();
#pragma unroll
        for (int kk = 0; kk < 32; kk += 4) {
            float4 w0 = *(const float4*)&Wsh[kk + 0][tx * 4];
            float4 w1 = *(const float4*)&Wsh[kk + 1][tx * 4];
            float4 w2 = *(const float4*)&Wsh[kk + 2][tx * 4];
            float4 w3 = *(const float4*)&Wsh[kk + 3][tx * 4];
#pragma unroll
            for (int rr = 0; rr < 8; ++rr) {
                float4 a = *(const float4*)&Ash[ty * 8 + rr][kk];
                acc[rr][0] += a.x * w0.x + a.y * w1.x + a.z * w2.x + a.w * w3.x;
                acc[rr][1] += a.x * w0.y + a.y * w1.y + a.z * w2.y + a.w * w3.y;
                acc[rr][2] += a.x * w0.z + a.y * w1.z + a.z * w2.z + a.w * w3.z;
                acc[rr][3] += a.x * w0.w + a.y * w1.w + a.z * w2.w + a.w * w3.w;
            }
        }
        __syncthreads();
    }

    int c = tx * 4;
    float4 bv = *(const float4*)(bias + c);
    float psum[4] = {0.f, 0.f, 0.f, 0.f};
    float psq[4] = {0.f, 0.f, 0.f, 0.f};
#pragma unroll
    for (int rr = 0; rr < 8; ++rr) {
        int grow = row0 + ty * 8 + rr;
        if (grow < NN) {
            float h0 = acc[rr][0] + bv.x;
            float h1 = acc[rr][1] + bv.y;
            float h2 = acc[rr][2] + bv.z;
            float h3 = acc[rr][3] + bv.w;
            float4 h = make_float4(h0, h1, h2, h3);
            *(float4*)(H + (size_t)grow * HH + c) = h;
            psum[0] += h0; psq[0] += h0 * h0;
            psum[1] += h1; psq[1] += h1 * h1;
            psum[2] += h2; psq[2] += h2 * h2;
            psum[3] += h3; psq[3] += h3 * h3;
        }
    }
#pragma unroll
    for (int q = 0; q < 4; ++q) {
        atomicAdd(&ssum[c + q], psum[q]);
        atomicAdd(&ssq[c + q], psq[q]);
    }
    __syncthreads();
    if (tid < HH) {
        atomicAdd(&gsum[tid], ssum[tid]);
        atomicAdd(&gsq[tid], ssq[tid]);
    }
}

__global__ void finalize_kernel(const float* __restrict__ gsum, const float* __restrict__ gsq,
                                const float* __restrict__ g, const float* __restrict__ beta,
                                float* __restrict__ ascale, float* __restrict__ bshift) {
    int t = threadIdx.x;
    if (t >= HH) return;
    float mu = gsum[t] / (float)NN;
    float var = gsq[t] / (float)NN - mu * mu;
    var = fmaxf(var, 0.f);
    float inv = rsqrtf(var + 1e-5f);
    float a = g[t] * inv;
    ascale[t] = a;
    bshift[t] = beta[t] - mu * a;
}

__global__ void apply_kernel(const float* __restrict__ Hin, const float* __restrict__ ascale,
                             const float* __restrict__ bshift, float* __restrict__ Xout) {
    int i = blockIdx.x * blockDim.x + threadIdx.x;   // float4 index
    if (i >= NN * (HH / 4)) return;
    int c4 = (i & 31) * 4;
    float4 h = ((const float4*)Hin)[i];
    float4 a = *(const float4*)(ascale + c4);
    float4 b = *(const float4*)(bshift + c4);
    float4 o;
    o.x = fmaxf(a.x * h.x + b.x, 0.f);
    o.y = fmaxf(a.y * h.y + b.y, 0.f);
    o.z = fmaxf(a.z * h.z + b.z, 0.f);
    o.w = fmaxf(a.w * h.w + b.w, 0.f);
    ((float4*)Xout)[i] = o;
}

// ---------------- pooling + fc ----------------

__global__ void bounds_kernel(const int* __restrict__ batch, int* gstart, int* gend) {
    int i = blockIdx.x * blockDim.x + threadIdx.x;
    if (i < NN) {
        int b = batch[i];
        if (b >= 0 && b < GG) {
            atomicMin(&gstart[b], i);
            atomicMax(&gend[b], i + 1);
        }
    }
}

__global__ void pool_kernel(const float* __restrict__ X, const int* __restrict__ gstart,
                            const int* __restrict__ gend, float* __restrict__ pooled) {
    int g = blockIdx.x;
    int t = threadIdx.x;
    int s = gstart[g], e = gend[g];
    float acc = 0.f;
    for (int i = s; i < e; ++i) acc += X[(size_t)i * HH + t];
    float out = 0.f;
    if (e > s) out = acc / fmaxf((float)(e - s), 1.f);
    pooled[g * HH + t] = out;
}

__global__ void fc_kernel(const float* __restrict__ pooled, const float* __restrict__ fc_w,
                          const float* __restrict__ fc_b, float* __restrict__ out) {
    int g = blockIdx.x;
    int o = threadIdx.x;
    float acc = fc_b[o];
    for (int k = 0; k < HH; ++k) acc += pooled[g * HH + k] * fc_w[k * HH + o];
    out[g * HH + o] = acc;
}

// ---------------- launch ----------------

extern "C" void kernel_launch(void* const* d_in, const int* in_sizes, int n_in,
                              void* d_out, int out_size, void* d_ws, size_t ws_size,
                              hipStream_t stream) {
    const float* x     = (const float*)d_in[0];
    const int*   ei    = (const int*)d_in[1];
    const int*   batch = (const int*)d_in[2];
    const float* Wl[3]    = {(const float*)d_in[3], (const float*)d_in[7], (const float*)d_in[11]};
    const float* bl[3]    = {(const float*)d_in[4], (const float*)d_in[8], (const float*)d_in[12]};
    const float* gl[3]    = {(const float*)d_in[5], (const float*)d_in[9], (const float*)d_in[13]};
    const float* betal[3] = {(const float*)d_in[6], (const float*)d_in[10], (const float*)d_in[14]};
    const float* fc_w = (const float*)d_in[15];
    const float* fc_b = (const float*)d_in[16];
    float* out = (float*)d_out;

    char* ws = (char*)d_ws;
    size_t off = 0;
    auto take = [&](size_t n) -> void* {
        void* p = ws + off;
        off = (off + n + 255) & ~(size_t)255;
        return p;
    };
    int*   deg       = (int*)take((size_t)NN * 4);
    int*   col_start = (int*)take((size_t)(NN + 1) * 4);
    int*   cursor    = (int*)take((size_t)NN * 4);
    float* dinv      = (float*)take((size_t)NN * 4);
    int*   srcv      = (int*)take((size_t)TOT * 4);
    float* wnorm     = (float*)take((size_t)TOT * 4);
    int*   bsums     = (int*)take(512 * 4);
    float* gsum      = (float*)take(HH * 4);
    float* gsq       = (float*)take(HH * 4);
    float* ascale    = (float*)take(HH * 4);
    float* bshift    = (float*)take(HH * 4);
    int*   gstart    = (int*)take(GG * 4);
    int*   gend      = (int*)take(GG * 4);
    float* pooled    = (float*)take((size_t)GG * HH * 4);
    float* B0        = (float*)take((size_t)NN * HH * 4);
    float* B1        = (float*)take((size_t)NN * HH * 4);

    const int nbScan = (NN + 255) / 256;   // 391

    init_kernel<<<(NN + 255) / 256, 256, 0, stream>>>(deg, gstart, gend);
    count_kernel<<<(EE + 255) / 256, 256, 0, stream>>>(ei, deg);
    dinv_kernel<<<(NN + 255) / 256, 256, 0, stream>>>(deg, dinv);
    scan1_kernel<<<nbScan, 256, 0, stream>>>(deg, col_start, bsums);
    scan2_kernel<<<1, 512, 0, stream>>>(bsums, nbScan);
    scan3_kernel<<<(NN + 256) / 256, 256, 0, stream>>>(col_start, bsums, cursor);
    fill_kernel<<<(TOT + 255) / 256, 256, 0, stream>>>(ei, dinv, cursor, srcv, wnorm);

    const float* cur = x;
    for (int l = 0; l < 3; ++l) {
        float* Abuf  = (l % 2 == 0) ? B0 : B1;
        float* Hbuf  = (l % 2 == 0) ? B1 : B0;
        float* Xnext = Abuf;
        zero_stats_kernel<<<1, 128, 0, stream>>>(gsum, gsq);
        agg_kernel<<<NN, 128, 0, stream>>>(cur, col_start, srcv, wnorm, Abuf);
        gemm_kernel<<<(NN + 63) / 64, 256, 0, stream>>>(Abuf, Wl[l], bl[l], Hbuf, gsum, gsq);
        finalize_kernel<<<1, 128, 0, stream>>>(gsum, gsq, gl[l], betal[l], ascale, bshift);
        apply_kernel<<<(NN * (HH / 4) + 255) / 256, 256, 0, stream>>>(Hbuf, ascale, bshift, Xnext);
        cur = Xnext;
    }

    bounds_kernel<<<(NN + 255) / 256, 256, 0, stream>>>(batch, gstart, gend);
    pool_kernel<<<GG, HH, 0, stream>>>(cur, gstart, gend, pooled);
    fc_kernel<<<GG, HH, 0, stream>>>(pooled, fc_w, fc_b, out);
}

// Round 3
// 1199.402 us; speedup vs baseline: 1.6715x; 1.6715x over previous
//
#include <hip/hip_runtime.h>

#define NN 100000
#define EE 1600000
#define HH 128
#define GG 64
#define TOT (EE + NN)
#define PSPLIT 8

// ---------------- graph prep ----------------

__global__ void init_kernel(int* deg, int* gstart, int* gend, float* poolsum) {
    int i = blockIdx.x * blockDim.x + threadIdx.x;
    if (i < NN) deg[i] = 1;               // self-loop
    if (i < GG) { gstart[i] = NN; gend[i] = 0; }
    if (i < GG * HH) poolsum[i] = 0.f;
}

__global__ void count_kernel(const int* __restrict__ ei, int* deg) {
    int e = blockIdx.x * blockDim.x + threadIdx.x;
    if (e < EE) {
        int c = ei[EE + e];
        if (c >= 0 && c < NN) atomicAdd(&deg[c], 1);   // col = target
    }
}

__global__ void dinv_kernel(const int* __restrict__ deg, float* __restrict__ dinv) {
    int i = blockIdx.x * blockDim.x + threadIdx.x;
    if (i < NN) dinv[i] = rsqrtf((float)deg[i]);  // deg >= 1 always
}

// exclusive scan of deg -> col_start (3 phases)
__global__ void scan1_kernel(const int* __restrict__ deg, int* __restrict__ out, int* __restrict__ bsums) {
    __shared__ int sh[256];
    int x = threadIdx.x;
    int i = blockIdx.x * 256 + x;
    int v = (i < NN) ? deg[i] : 0;
    sh[x] = v;
    __syncthreads();
    for (int off = 1; off < 256; off <<= 1) {
        int t = (x >= off) ? sh[x - off] : 0;
        __syncthreads();
        sh[x] += t;
        __syncthreads();
    }
    if (i < NN) out[i] = sh[x] - v;     // block-local exclusive
    if (x == 255) bsums[blockIdx.x] = sh[255];
}

__global__ void scan2_kernel(int* __restrict__ bsums, int nb) {
    __shared__ int sh[512];
    int x = threadIdx.x;
    int v = (x < nb) ? bsums[x] : 0;
    sh[x] = v;
    __syncthreads();
    for (int off = 1; off < 512; off <<= 1) {
        int t = (x >= off) ? sh[x - off] : 0;
        __syncthreads();
        sh[x] += t;
        __syncthreads();
    }
    if (x < nb) bsums[x] = sh[x] - v;   // exclusive
}

__global__ void scan3_kernel(int* __restrict__ col_start, const int* __restrict__ bsums, int* __restrict__ cursor) {
    int i = blockIdx.x * blockDim.x + threadIdx.x;
    if (i < NN) {
        int v = col_start[i] + bsums[i >> 8];
        col_start[i] = v;
        cursor[i] = v;
    } else if (i == NN) {
        col_start[NN] = TOT;
    }
}

__global__ void fill_kernel(const int* __restrict__ ei, const float* __restrict__ dinv,
                            int* cursor, int* __restrict__ srcv, float* __restrict__ wnorm) {
    int e = blockIdx.x * blockDim.x + threadIdx.x;
    int r, c;
    if (e < EE) { r = ei[e]; c = ei[EE + e]; }
    else if (e < TOT) { r = c = e - EE; }
    else return;
    int slot = atomicAdd(&cursor[c], 1);
    if (slot >= 0 && slot < TOT) {       // defensive: never OOB even if inputs are weird
        srcv[slot] = r;
        wnorm[slot] = dinv[r] * dinv[c];
    }
}

// batch is sorted -> group bounds are run boundaries; plain stores, no atomics.
__global__ void bounds_kernel(const int* __restrict__ batch, int* gstart, int* gend) {
    int i = blockIdx.x * blockDim.x + threadIdx.x;
    if (i >= NN) return;
    int b = batch[i];
    if (i == 0) {
        gstart[b] = 0;
    } else {
        int bp = batch[i - 1];
        if (b != bp) {
            gstart[b] = i;
            gend[bp] = i;
        }
    }
    if (i == NN - 1) gend[b] = NN;
}

// ---------------- per-layer kernels ----------------

// one wave per destination node; neighbor (src,w) lane-preloaded, shfl-broadcast
__global__ __launch_bounds__(256) void agg_kernel(const float* __restrict__ X,
                                                  const int* __restrict__ col_start,
                                                  const int* __restrict__ srcv,
                                                  const float* __restrict__ wnorm,
                                                  float* __restrict__ A) {
    int wid = (int)((blockIdx.x * blockDim.x + threadIdx.x) >> 6);
    int lane = threadIdx.x & 63;
    if (wid >= NN) return;
    int s0 = col_start[wid], s1 = col_start[wid + 1];
    const float2* __restrict__ X2 = (const float2*)X;
    float2 acc = make_float2(0.f, 0.f);
    for (int base = s0; base < s1; base += 64) {
        int cnt = min(64, s1 - base);
        int msrc = 0;
        float mw = 0.f;
        if (lane < cnt) { msrc = srcv[base + lane]; mw = wnorm[base + lane]; }
        for (int j = 0; j < cnt; ++j) {
            int src = __shfl(msrc, j);
            float w = __shfl(mw, j);
            float2 v = X2[(size_t)src * 64 + lane];
            acc.x += w * v.x;
            acc.y += w * v.y;
        }
    }
    ((float2*)A)[(size_t)wid * 64 + lane] = acc;
}

__global__ void zero_stats_kernel(float* gsum, float* gsq) {
    int t = threadIdx.x;
    if (t < HH) { gsum[t] = 0.f; gsq[t] = 0.f; }
}

// H = A @ W + b ; accumulate column sum/sumsq for BN
__global__ __launch_bounds__(256) void gemm_kernel(const float* __restrict__ A,
                                                   const float* __restrict__ W,
                                                   const float* __restrict__ bias,
                                                   float* __restrict__ H,
                                                   float* __restrict__ gsum,
                                                   float* __restrict__ gsq) {
    __shared__ float Ash[64][36];     // 36: keeps float4 rows 16B-aligned, breaks pow2 stride
    __shared__ float Wsh[32][HH];
    __shared__ float ssum[HH], ssq[HH];
    int tid = threadIdx.x;
    int ty = tid >> 5, tx = tid & 31;
    int row0 = blockIdx.x * 64;
    if (tid < HH) { ssum[tid] = 0.f; ssq[tid] = 0.f; }

    float acc[8][4];
#pragma unroll
    for (int r = 0; r < 8; ++r)
#pragma unroll
        for (int q = 0; q < 4; ++q) acc[r][q] = 0.f;

    for (int kt = 0; kt < 4; ++kt) {
        int k0 = kt * 32;
        // stage W tile 32x128
        {
            int r = tid >> 3;
            int cg = (tid & 7) * 16;
            const float4* wp = (const float4*)(W + (size_t)(k0 + r) * HH + cg);
            float4 w0 = wp[0], w1 = wp[1], w2 = wp[2], w3 = wp[3];
            *(float4*)&Wsh[r][cg + 0]  = w0;
            *(float4*)&Wsh[r][cg + 4]  = w1;
            *(float4*)&Wsh[r][cg + 8]  = w2;
            *(float4*)&Wsh[r][cg + 12] = w3;
        }
        // stage A tile 64x32
        {
            int r = tid >> 2;
            int q = tid & 3;
            int grow = row0 + r;
            float4 a0 = make_float4(0.f, 0.f, 0.f, 0.f), a1 = a0;
            if (grow < NN) {
                const float4* ap = (const float4*)(A + (size_t)grow * HH + k0 + q * 8);
                a0 = ap[0]; a1 = ap[1];
            }
            *(float4*)&Ash[r][q * 8 + 0] = a0;
            *(float4*)&Ash[r][q * 8 + 4] = a1;
        }
        __syncthreads();
#pragma unroll
        for (int kk = 0; kk < 32; kk += 4) {
            float4 w0 = *(const float4*)&Wsh[kk + 0][tx * 4];
            float4 w1 = *(const float4*)&Wsh[kk + 1][tx * 4];
            float4 w2 = *(const float4*)&Wsh[kk + 2][tx * 4];
            float4 w3 = *(const float4*)&Wsh[kk + 3][tx * 4];
#pragma unroll
            for (int rr = 0; rr < 8; ++rr) {
                float4 a = *(const float4*)&Ash[ty * 8 + rr][kk];
                acc[rr][0] += a.x * w0.x + a.y * w1.x + a.z * w2.x + a.w * w3.x;
                acc[rr][1] += a.x * w0.y + a.y * w1.y + a.z * w2.y + a.w * w3.y;
                acc[rr][2] += a.x * w0.z + a.y * w1.z + a.z * w2.z + a.w * w3.z;
                acc[rr][3] += a.x * w0.w + a.y * w1.w + a.z * w2.w + a.w * w3.w;
            }
        }
        __syncthreads();
    }

    int c = tx * 4;
    float4 bv = *(const float4*)(bias + c);
    float psum[4] = {0.f, 0.f, 0.f, 0.f};
    float psq[4] = {0.f, 0.f, 0.f, 0.f};
#pragma unroll
    for (int rr = 0; rr < 8; ++rr) {
        int grow = row0 + ty * 8 + rr;
        if (grow < NN) {
            float h0 = acc[rr][0] + bv.x;
            float h1 = acc[rr][1] + bv.y;
            float h2 = acc[rr][2] + bv.z;
            float h3 = acc[rr][3] + bv.w;
            float4 h = make_float4(h0, h1, h2, h3);
            *(float4*)(H + (size_t)grow * HH + c) = h;
            psum[0] += h0; psq[0] += h0 * h0;
            psum[1] += h1; psq[1] += h1 * h1;
            psum[2] += h2; psq[2] += h2 * h2;
            psum[3] += h3; psq[3] += h3 * h3;
        }
    }
#pragma unroll
    for (int q = 0; q < 4; ++q) {
        atomicAdd(&ssum[c + q], psum[q]);
        atomicAdd(&ssq[c + q], psq[q]);
    }
    __syncthreads();
    if (tid < HH) {
        atomicAdd(&gsum[tid], ssum[tid]);
        atomicAdd(&gsq[tid], ssq[tid]);
    }
}

__global__ void finalize_kernel(const float* __restrict__ gsum, const float* __restrict__ gsq,
                                const float* __restrict__ g, const float* __restrict__ beta,
                                float* __restrict__ ascale, float* __restrict__ bshift) {
    int t = threadIdx.x;
    if (t >= HH) return;
    float mu = gsum[t] / (float)NN;
    float var = gsq[t] / (float)NN - mu * mu;
    var = fmaxf(var, 0.f);
    float inv = rsqrtf(var + 1e-5f);
    float a = g[t] * inv;
    ascale[t] = a;
    bshift[t] = beta[t] - mu * a;
}

__global__ void apply_kernel(const float* __restrict__ Hin, const float* __restrict__ ascale,
                             const float* __restrict__ bshift, float* __restrict__ Xout) {
    int i = blockIdx.x * blockDim.x + threadIdx.x;   // float4 index
    if (i >= NN * (HH / 4)) return;
    int c4 = (i & 31) * 4;
    float4 h = ((const float4*)Hin)[i];
    float4 a = *(const float4*)(ascale + c4);
    float4 b = *(const float4*)(bshift + c4);
    float4 o;
    o.x = fmaxf(a.x * h.x + b.x, 0.f);
    o.y = fmaxf(a.y * h.y + b.y, 0.f);
    o.z = fmaxf(a.z * h.z + b.z, 0.f);
    o.w = fmaxf(a.w * h.w + b.w, 0.f);
    ((float4*)Xout)[i] = o;
}

// ---------------- pooling + fc ----------------

__global__ void pool_kernel(const float* __restrict__ X, const int* __restrict__ gstart,
                            const int* __restrict__ gend, float* __restrict__ poolsum) {
    int g = blockIdx.x;
    int sp = blockIdx.y;
    int t = threadIdx.x;           // 128
    int s = gstart[g], e = gend[g];
    if (e <= s) return;
    int len = e - s;
    int chunk = (len + PSPLIT - 1) / PSPLIT;
    int cs = s + sp * chunk;
    int ce = min(cs + chunk, e);
    if (cs >= ce) return;
    float acc = 0.f;
    for (int i = cs; i < ce; ++i) acc += X[(size_t)i * HH + t];
    atomicAdd(&poolsum[g * HH + t], acc);
}

__global__ void fc_kernel(const float* __restrict__ poolsum, const int* __restrict__ gstart,
                          const int* __restrict__ gend, const float* __restrict__ fc_w,
                          const float* __restrict__ fc_b, float* __restrict__ out) {
    int g = blockIdx.x;
    int o = threadIdx.x;
    int cnt = gend[g] - gstart[g];
    float inv = (cnt > 0) ? (1.f / (float)cnt) : 0.f;
    float acc = fc_b[o];
    for (int k = 0; k < HH; ++k) acc += (poolsum[g * HH + k] * inv) * fc_w[k * HH + o];
    out[g * HH + o] = acc;
}

// ---------------- launch ----------------

extern "C" void kernel_launch(void* const* d_in, const int* in_sizes, int n_in,
                              void* d_out, int out_size, void* d_ws, size_t ws_size,
                              hipStream_t stream) {
    const float* x     = (const float*)d_in[0];
    const int*   ei    = (const int*)d_in[1];
    const int*   batch = (const int*)d_in[2];
    const float* Wl[3]    = {(const float*)d_in[3], (const float*)d_in[7], (const float*)d_in[11]};
    const float* bl[3]    = {(const float*)d_in[4], (const float*)d_in[8], (const float*)d_in[12]};
    const float* gl[3]    = {(const float*)d_in[5], (const float*)d_in[9], (const float*)d_in[13]};
    const float* betal[3] = {(const float*)d_in[6], (const float*)d_in[10], (const float*)d_in[14]};
    const float* fc_w = (const float*)d_in[15];
    const float* fc_b = (const float*)d_in[16];
    float* out = (float*)d_out;

    char* ws = (char*)d_ws;
    size_t off = 0;
    auto take = [&](size_t n) -> void* {
        void* p = ws + off;
        off = (off + n + 255) & ~(size_t)255;
        return p;
    };
    int*   deg       = (int*)take((size_t)NN * 4);
    int*   col_start = (int*)take((size_t)(NN + 1) * 4);
    int*   cursor    = (int*)take((size_t)NN * 4);
    float* dinv      = (float*)take((size_t)NN * 4);
    int*   srcv      = (int*)take((size_t)TOT * 4);
    float* wnorm     = (float*)take((size_t)TOT * 4);
    int*   bsums     = (int*)take(512 * 4);
    float* gsum      = (float*)take(HH * 4);
    float* gsq       = (float*)take(HH * 4);
    float* ascale    = (float*)take(HH * 4);
    float* bshift    = (float*)take(HH * 4);
    int*   gstart    = (int*)take(GG * 4);
    int*   gend      = (int*)take(GG * 4);
    float* poolsum   = (float*)take((size_t)GG * HH * 4);
    float* B0        = (float*)take((size_t)NN * HH * 4);
    float* B1        = (float*)take((size_t)NN * HH * 4);

    const int nbScan = (NN + 255) / 256;   // 391

    init_kernel<<<(NN + 255) / 256, 256, 0, stream>>>(deg, gstart, gend, poolsum);
    count_kernel<<<(EE + 255) / 256, 256, 0, stream>>>(ei, deg);
    dinv_kernel<<<(NN + 255) / 256, 256, 0, stream>>>(deg, dinv);
    scan1_kernel<<<nbScan, 256, 0, stream>>>(deg, col_start, bsums);
    scan2_kernel<<<1, 512, 0, stream>>>(bsums, nbScan);
    scan3_kernel<<<(NN + 256) / 256, 256, 0, stream>>>(col_start, bsums, cursor);
    fill_kernel<<<(TOT + 255) / 256, 256, 0, stream>>>(ei, dinv, cursor, srcv, wnorm);
    bounds_kernel<<<(NN + 255) / 256, 256, 0, stream>>>(batch, gstart, gend);

    const float* cur = x;
    for (int l = 0; l < 3; ++l) {
        float* Abuf  = (l % 2 == 0) ? B0 : B1;
        float* Hbuf  = (l % 2 == 0) ? B1 : B0;
        float* Xnext = Abuf;
        zero_stats_kernel<<<1, 128, 0, stream>>>(gsum, gsq);
        agg_kernel<<<(NN * 64 + 255) / 256, 256, 0, stream>>>(cur, col_start, srcv, wnorm, Abuf);
        gemm_kernel<<<(NN + 63) / 64, 256, 0, stream>>>(Abuf, Wl[l], bl[l], Hbuf, gsum, gsq);
        finalize_kernel<<<1, 128, 0, stream>>>(gsum, gsq, gl[l], betal[l], ascale, bshift);
        apply_kernel<<<(NN * (HH / 4) + 255) / 256, 256, 0, stream>>>(Hbuf, ascale, bshift, Xnext);
        cur = Xnext;
    }

    pool_kernel<<<dim3(GG, PSPLIT), 128, 0, stream>>>(cur, gstart, gend, poolsum);
    fc_kernel<<<GG, 128, 0, stream>>>(poolsum, gstart, gend, fc_w, fc_b, out);
}

// Round 4
// 937.363 us; speedup vs baseline: 2.1388x; 1.2795x over previous
//
#include <hip/hip_runtime.h>

#define NN 100000
#define EE 1600000
#define HH 128
#define GG 64
#define TOT (EE + NN)
#define PSPLIT 8

typedef __attribute__((ext_vector_type(8))) short s16x8;
typedef __attribute__((ext_vector_type(4))) float f32x4;

__device__ __forceinline__ unsigned short f2bf(float f) {
    unsigned u = __float_as_uint(f);
    u = u + 0x7FFFu + ((u >> 16) & 1u);   // round-to-nearest-even
    return (unsigned short)(u >> 16);
}

// ---------------- graph prep ----------------

__global__ void init_kernel(int* deg, int* gstart, int* gend, float* poolsum) {
    int i = blockIdx.x * blockDim.x + threadIdx.x;
    if (i < NN) deg[i] = 1;               // self-loop
    if (i < GG) { gstart[i] = NN; gend[i] = 0; }
    if (i < GG * HH) poolsum[i] = 0.f;
}

__global__ void count_kernel(const int* __restrict__ ei, int* deg) {
    int e = blockIdx.x * blockDim.x + threadIdx.x;
    if (e < EE) {
        int c = ei[EE + e];
        if (c >= 0 && c < NN) atomicAdd(&deg[c], 1);   // col = target
    }
}

__global__ void dinv_kernel(const int* __restrict__ deg, float* __restrict__ dinv) {
    int i = blockIdx.x * blockDim.x + threadIdx.x;
    if (i < NN) dinv[i] = rsqrtf((float)deg[i]);  // deg >= 1 always
}

// exclusive scan of deg -> col_start (3 phases)
__global__ void scan1_kernel(const int* __restrict__ deg, int* __restrict__ out, int* __restrict__ bsums) {
    __shared__ int sh[256];
    int x = threadIdx.x;
    int i = blockIdx.x * 256 + x;
    int v = (i < NN) ? deg[i] : 0;
    sh[x] = v;
    __syncthreads();
    for (int off = 1; off < 256; off <<= 1) {
        int t = (x >= off) ? sh[x - off] : 0;
        __syncthreads();
        sh[x] += t;
        __syncthreads();
    }
    if (i < NN) out[i] = sh[x] - v;     // block-local exclusive
    if (x == 255) bsums[blockIdx.x] = sh[255];
}

__global__ void scan2_kernel(int* __restrict__ bsums, int nb) {
    __shared__ int sh[512];
    int x = threadIdx.x;
    int v = (x < nb) ? bsums[x] : 0;
    sh[x] = v;
    __syncthreads();
    for (int off = 1; off < 512; off <<= 1) {
        int t = (x >= off) ? sh[x - off] : 0;
        __syncthreads();
        sh[x] += t;
        __syncthreads();
    }
    if (x < nb) bsums[x] = sh[x] - v;   // exclusive
}

__global__ void scan3_kernel(int* __restrict__ col_start, const int* __restrict__ bsums, int* __restrict__ cursor) {
    int i = blockIdx.x * blockDim.x + threadIdx.x;
    if (i < NN) {
        int v = col_start[i] + bsums[i >> 8];
        col_start[i] = v;
        cursor[i] = v;
    } else if (i == NN) {
        col_start[NN] = TOT;
    }
}

// pack (src, wnorm) into one 8B store: halves random cache-line touches vs two arrays
__global__ void fill_kernel(const int* __restrict__ ei, const float* __restrict__ dinv,
                            int* cursor, int2* __restrict__ pairs) {
    int e = blockIdx.x * blockDim.x + threadIdx.x;
    int r, c;
    if (e < EE) { r = ei[e]; c = ei[EE + e]; }
    else if (e < TOT) { r = c = e - EE; }
    else return;
    int slot = atomicAdd(&cursor[c], 1);
    if (slot >= 0 && slot < TOT) {
        pairs[slot] = make_int2(r, __float_as_int(dinv[r] * dinv[c]));
    }
}

// batch is sorted -> group bounds are run boundaries; plain stores, no atomics.
__global__ void bounds_kernel(const int* __restrict__ batch, int* gstart, int* gend) {
    int i = blockIdx.x * blockDim.x + threadIdx.x;
    if (i >= NN) return;
    int b = batch[i];
    if (i == 0) {
        gstart[b] = 0;
    } else {
        int bp = batch[i - 1];
        if (b != bp) {
            gstart[b] = i;
            gend[bp] = i;
        }
    }
    if (i == NN - 1) gend[b] = NN;
}

// cast+transpose W (fp32 row-major [k][n]) -> Wt bf16 [n][k]
__global__ void wprep_kernel(const float* __restrict__ W, unsigned short* __restrict__ Wt) {
    int i = blockIdx.x * 256 + threadIdx.x;
    if (i < HH * HH) {
        int k = i >> 7, n = i & 127;
        Wt[n * HH + k] = f2bf(W[i]);
    }
}

// ---------------- per-layer kernels ----------------

// one wave per destination node; neighbor (src,w) lane-preloaded, shfl-broadcast.
// fp32 accumulate, bf16 output (feeds MFMA gemm).
__global__ __launch_bounds__(256) void agg_kernel(const float* __restrict__ X,
                                                  const int* __restrict__ col_start,
                                                  const int2* __restrict__ pairs,
                                                  unsigned short* __restrict__ Abf) {
    int wid = (int)((blockIdx.x * blockDim.x + threadIdx.x) >> 6);
    int lane = threadIdx.x & 63;
    if (wid >= NN) return;
    int s0 = col_start[wid], s1 = col_start[wid + 1];
    const float2* __restrict__ X2 = (const float2*)X;
    float2 acc = make_float2(0.f, 0.f);
    for (int base = s0; base < s1; base += 64) {
        int cnt = min(64, s1 - base);
        int2 p = make_int2(0, 0);
        if (lane < cnt) p = pairs[base + lane];
        for (int j = 0; j < cnt; ++j) {
            int src = __shfl(p.x, j);
            float w = __shfl(__int_as_float(p.y), j);
            float2 v = X2[(size_t)src * 64 + lane];
            acc.x += w * v.x;
            acc.y += w * v.y;
        }
    }
    unsigned pk = (unsigned)f2bf(acc.x) | ((unsigned)f2bf(acc.y) << 16);
    ((unsigned*)Abf)[(size_t)wid * 64 + lane] = pk;
}

__global__ void zero_stats_kernel(float* gsum, float* gsq) {
    int t = threadIdx.x;
    if (t < HH) { gsum[t] = 0.f; gsq[t] = 0.f; }
}

// H = Abf @ W + b via bf16 MFMA 16x16x32; fused column sum/sumsq for BN.
// Block: 256 threads = 4 waves, 128 rows. Wt (bf16, [n][k]) staged to LDS, +8 pad.
__global__ __launch_bounds__(256) void gemm_kernel(const unsigned short* __restrict__ Abf,
                                                   const unsigned short* __restrict__ Wt,
                                                   const float* __restrict__ bias,
                                                   float* __restrict__ H,
                                                   float* __restrict__ gsum,
                                                   float* __restrict__ gsq) {
    __shared__ unsigned short wlds[128 * 136];   // row stride 136 bf16 = 272B (17*16B): no b128 conflicts
    __shared__ float ssum[HH], ssq[HH];
    int tid = threadIdx.x;
    if (tid < HH) { ssum[tid] = 0.f; ssq[tid] = 0.f; }
#pragma unroll
    for (int it = 0; it < 16; ++it) {            // stage 32KB Wt, coalesced, conflict-free
        int idx = it * 256 + tid;
        int r = idx >> 5, c = idx & 31;
        *(uint2*)&wlds[r * 136 + c * 4] = *(const uint2*)(Wt + r * HH + c * 4);
    }
    __syncthreads();

    int lane = tid & 63;
    int wave = tid >> 6;
    int mcol = lane & 15;
    int quad = lane >> 4;
    int rowbase = blockIdx.x * 128 + wave * 32;
    int row0 = rowbase + mcol;
    int row1 = row0 + 16;

    f32x4 acc[2][8];
#pragma unroll
    for (int mt = 0; mt < 2; ++mt)
#pragma unroll
        for (int nt = 0; nt < 8; ++nt) acc[mt][nt] = (f32x4){0.f, 0.f, 0.f, 0.f};

    s16x8 zf = {0, 0, 0, 0, 0, 0, 0, 0};
#pragma unroll
    for (int ks = 0; ks < 4; ++ks) {
        int k0 = ks * 32 + quad * 8;
        s16x8 a0 = (row0 < NN) ? *(const s16x8*)(Abf + (size_t)row0 * HH + k0) : zf;
        s16x8 a1 = (row1 < NN) ? *(const s16x8*)(Abf + (size_t)row1 * HH + k0) : zf;
#pragma unroll
        for (int nt = 0; nt < 8; ++nt) {
            s16x8 b = *(const s16x8*)&wlds[(nt * 16 + mcol) * 136 + k0];
            acc[0][nt] = __builtin_amdgcn_mfma_f32_16x16x32_bf16(a0, b, acc[0][nt], 0, 0, 0);
            acc[1][nt] = __builtin_amdgcn_mfma_f32_16x16x32_bf16(a1, b, acc[1][nt], 0, 0, 0);
        }
    }

    // epilogue: bias add, store, per-col stats (C/D: col=lane&15, row=quad*4+reg)
    float s[8], sq[8];
#pragma unroll
    for (int nt = 0; nt < 8; ++nt) { s[nt] = 0.f; sq[nt] = 0.f; }
#pragma unroll
    for (int mt = 0; mt < 2; ++mt) {
        int rbase = rowbase + mt * 16 + quad * 4;
#pragma unroll
        for (int nt = 0; nt < 8; ++nt) {
            int col = nt * 16 + mcol;
            float bv = bias[col];
            f32x4 a = acc[mt][nt];
#pragma unroll
            for (int reg = 0; reg < 4; ++reg) {
                int r = rbase + reg;
                if (r < NN) {
                    float h = a[reg] + bv;
                    H[(size_t)r * HH + col] = h;
                    s[nt] += h; sq[nt] += h * h;
                }
            }
        }
    }
#pragma unroll
    for (int nt = 0; nt < 8; ++nt) {
        float v = s[nt];  v += __shfl_xor(v, 16);  v += __shfl_xor(v, 32);
        float w = sq[nt]; w += __shfl_xor(w, 16);  w += __shfl_xor(w, 32);
        if (quad == 0) {
            atomicAdd(&ssum[nt * 16 + mcol], v);
            atomicAdd(&ssq[nt * 16 + mcol], w);
        }
    }
    __syncthreads();
    if (tid < HH) {
        atomicAdd(&gsum[tid], ssum[tid]);
        atomicAdd(&gsq[tid], ssq[tid]);
    }
}

__global__ void finalize_kernel(const float* __restrict__ gsum, const float* __restrict__ gsq,
                                const float* __restrict__ g, const float* __restrict__ beta,
                                float* __restrict__ ascale, float* __restrict__ bshift) {
    int t = threadIdx.x;
    if (t >= HH) return;
    float mu = gsum[t] / (float)NN;
    float var = gsq[t] / (float)NN - mu * mu;
    var = fmaxf(var, 0.f);
    float inv = rsqrtf(var + 1e-5f);
    float a = g[t] * inv;
    ascale[t] = a;
    bshift[t] = beta[t] - mu * a;
}

// in-place BN affine + ReLU over H (becomes X for next layer)
__global__ void apply_kernel(float* __restrict__ HX, const float* __restrict__ ascale,
                             const float* __restrict__ bshift) {
    int i = blockIdx.x * blockDim.x + threadIdx.x;   // float4 index
    if (i >= NN * (HH / 4)) return;
    int c4 = (i & 31) * 4;
    float4 h = ((const float4*)HX)[i];
    float4 a = *(const float4*)(ascale + c4);
    float4 b = *(const float4*)(bshift + c4);
    float4 o;
    o.x = fmaxf(a.x * h.x + b.x, 0.f);
    o.y = fmaxf(a.y * h.y + b.y, 0.f);
    o.z = fmaxf(a.z * h.z + b.z, 0.f);
    o.w = fmaxf(a.w * h.w + b.w, 0.f);
    ((float4*)HX)[i] = o;
}

// ---------------- pooling + fc ----------------

__global__ void pool_kernel(const float* __restrict__ X, const int* __restrict__ gstart,
                            const int* __restrict__ gend, float* __restrict__ poolsum) {
    int g = blockIdx.x;
    int sp = blockIdx.y;
    int t = threadIdx.x;           // 128
    int s = gstart[g], e = gend[g];
    if (e <= s) return;
    int len = e - s;
    int chunk = (len + PSPLIT - 1) / PSPLIT;
    int cs = s + sp * chunk;
    int ce = min(cs + chunk, e);
    if (cs >= ce) return;
    float acc = 0.f;
    for (int i = cs; i < ce; ++i) acc += X[(size_t)i * HH + t];
    atomicAdd(&poolsum[g * HH + t], acc);
}

__global__ void fc_kernel(const float* __restrict__ poolsum, const int* __restrict__ gstart,
                          const int* __restrict__ gend, const float* __restrict__ fc_w,
                          const float* __restrict__ fc_b, float* __restrict__ out) {
    int g = blockIdx.x;
    int o = threadIdx.x;
    int cnt = gend[g] - gstart[g];
    float inv = (cnt > 0) ? (1.f / (float)cnt) : 0.f;
    float acc = fc_b[o];
    for (int k = 0; k < HH; ++k) acc += (poolsum[g * HH + k] * inv) * fc_w[k * HH + o];
    out[g * HH + o] = acc;
}

// ---------------- launch ----------------

extern "C" void kernel_launch(void* const* d_in, const int* in_sizes, int n_in,
                              void* d_out, int out_size, void* d_ws, size_t ws_size,
                              hipStream_t stream) {
    const float* x     = (const float*)d_in[0];
    const int*   ei    = (const int*)d_in[1];
    const int*   batch = (const int*)d_in[2];
    const float* Wl[3]    = {(const float*)d_in[3], (const float*)d_in[7], (const float*)d_in[11]};
    const float* bl[3]    = {(const float*)d_in[4], (const float*)d_in[8], (const float*)d_in[12]};
    const float* gl[3]    = {(const float*)d_in[5], (const float*)d_in[9], (const float*)d_in[13]};
    const float* betal[3] = {(const float*)d_in[6], (const float*)d_in[10], (const float*)d_in[14]};
    const float* fc_w = (const float*)d_in[15];
    const float* fc_b = (const float*)d_in[16];
    float* out = (float*)d_out;

    char* ws = (char*)d_ws;
    size_t off = 0;
    auto take = [&](size_t n) -> void* {
        void* p = ws + off;
        off = (off + n + 255) & ~(size_t)255;
        return p;
    };
    int*   deg       = (int*)take((size_t)NN * 4);
    int*   col_start = (int*)take((size_t)(NN + 1) * 4);
    int*   cursor    = (int*)take((size_t)NN * 4);
    float* dinv      = (float*)take((size_t)NN * 4);
    int2*  pairs     = (int2*)take((size_t)TOT * 8);
    int*   bsums     = (int*)take(512 * 4);
    float* gsum      = (float*)take(HH * 4);
    float* gsq       = (float*)take(HH * 4);
    float* ascale    = (float*)take(HH * 4);
    float* bshift    = (float*)take(HH * 4);
    int*   gstart    = (int*)take(GG * 4);
    int*   gend      = (int*)take(GG * 4);
    float* poolsum   = (float*)take((size_t)GG * HH * 4);
    unsigned short* wt = (unsigned short*)take((size_t)3 * HH * HH * 2);
    unsigned short* Abf = (unsigned short*)take((size_t)NN * HH * 2);
    float* Hbuf      = (float*)take((size_t)NN * HH * 4);

    const int nbScan = (NN + 255) / 256;   // 391

    init_kernel<<<(NN + 255) / 256, 256, 0, stream>>>(deg, gstart, gend, poolsum);
    count_kernel<<<(EE + 255) / 256, 256, 0, stream>>>(ei, deg);
    dinv_kernel<<<(NN + 255) / 256, 256, 0, stream>>>(deg, dinv);
    scan1_kernel<<<nbScan, 256, 0, stream>>>(deg, col_start, bsums);
    scan2_kernel<<<1, 512, 0, stream>>>(bsums, nbScan);
    scan3_kernel<<<(NN + 256) / 256, 256, 0, stream>>>(col_start, bsums, cursor);
    fill_kernel<<<(TOT + 255) / 256, 256, 0, stream>>>(ei, dinv, cursor, pairs);
    bounds_kernel<<<(NN + 255) / 256, 256, 0, stream>>>(batch, gstart, gend);
    for (int l = 0; l < 3; ++l)
        wprep_kernel<<<(HH * HH + 255) / 256, 256, 0, stream>>>(Wl[l], wt + (size_t)l * HH * HH);

    const float* cur = x;
    for (int l = 0; l < 3; ++l) {
        zero_stats_kernel<<<1, 128, 0, stream>>>(gsum, gsq);
        agg_kernel<<<(NN * 64 + 255) / 256, 256, 0, stream>>>(cur, col_start, pairs, Abf);
        gemm_kernel<<<(NN + 127) / 128, 256, 0, stream>>>(Abf, wt + (size_t)l * HH * HH, bl[l],
                                                          Hbuf, gsum, gsq);
        finalize_kernel<<<1, 128, 0, stream>>>(gsum, gsq, gl[l], betal[l], ascale, bshift);
        apply_kernel<<<(NN * (HH / 4) + 255) / 256, 256, 0, stream>>>(Hbuf, ascale, bshift);
        cur = Hbuf;
    }

    pool_kernel<<<dim3(GG, PSPLIT), 128, 0, stream>>>(cur, gstart, gend, poolsum);
    fc_kernel<<<GG, 128, 0, stream>>>(poolsum, gstart, gend, fc_w, fc_b, out);
}

// Round 5
// 858.417 us; speedup vs baseline: 2.3355x; 1.0920x over previous
//
#include <hip/hip_runtime.h>

#define NN 100000
#define EE 1600000
#define HH 128
#define GG 64
#define TOT (EE + NN)
#define PSPLIT 8

typedef __attribute__((ext_vector_type(8))) short s16x8;
typedef __attribute__((ext_vector_type(4))) float f32x4;

__device__ __forceinline__ unsigned short f2bf(float f) {
    unsigned u = __float_as_uint(f);
    u = u + 0x7FFFu + ((u >> 16) & 1u);   // round-to-nearest-even
    return (unsigned short)(u >> 16);
}

// ---------------- graph prep ----------------

__global__ void init_kernel(int* deg, int* gstart, int* gend, float* poolsum) {
    int i = blockIdx.x * blockDim.x + threadIdx.x;
    if (i < NN) deg[i] = 1;               // self-loop
    if (i < GG) { gstart[i] = NN; gend[i] = 0; }
    if (i < GG * HH) poolsum[i] = 0.f;
}

__global__ void count_kernel(const int* __restrict__ ei, int* deg) {
    int e = blockIdx.x * blockDim.x + threadIdx.x;
    if (e < EE) {
        int c = ei[EE + e];
        if (c >= 0 && c < NN) atomicAdd(&deg[c], 1);   // col = target
    }
}

__global__ void dinv_kernel(const int* __restrict__ deg, float* __restrict__ dinv) {
    int i = blockIdx.x * blockDim.x + threadIdx.x;
    if (i < NN) dinv[i] = rsqrtf((float)deg[i]);  // deg >= 1 always
}

// exclusive scan of deg -> col_start (3 phases)
__global__ void scan1_kernel(const int* __restrict__ deg, int* __restrict__ out, int* __restrict__ bsums) {
    __shared__ int sh[256];
    int x = threadIdx.x;
    int i = blockIdx.x * 256 + x;
    int v = (i < NN) ? deg[i] : 0;
    sh[x] = v;
    __syncthreads();
    for (int off = 1; off < 256; off <<= 1) {
        int t = (x >= off) ? sh[x - off] : 0;
        __syncthreads();
        sh[x] += t;
        __syncthreads();
    }
    if (i < NN) out[i] = sh[x] - v;     // block-local exclusive
    if (x == 255) bsums[blockIdx.x] = sh[255];
}

__global__ void scan2_kernel(int* __restrict__ bsums, int nb) {
    __shared__ int sh[512];
    int x = threadIdx.x;
    int v = (x < nb) ? bsums[x] : 0;
    sh[x] = v;
    __syncthreads();
    for (int off = 1; off < 512; off <<= 1) {
        int t = (x >= off) ? sh[x - off] : 0;
        __syncthreads();
        sh[x] += t;
        __syncthreads();
    }
    if (x < nb) bsums[x] = sh[x] - v;   // exclusive
}

__global__ void scan3_kernel(int* __restrict__ col_start, const int* __restrict__ bsums, int* __restrict__ cursor) {
    int i = blockIdx.x * blockDim.x + threadIdx.x;
    if (i < NN) {
        int v = col_start[i] + bsums[i >> 8];
        col_start[i] = v;
        cursor[i] = v;
    } else if (i == NN) {
        col_start[NN] = TOT;
    }
}

// pack (src, wnorm) into one 8B store: halves random cache-line touches vs two arrays
__global__ void fill_kernel(const int* __restrict__ ei, const float* __restrict__ dinv,
                            int* cursor, int2* __restrict__ pairs) {
    int e = blockIdx.x * blockDim.x + threadIdx.x;
    int r, c;
    if (e < EE) { r = ei[e]; c = ei[EE + e]; }
    else if (e < TOT) { r = c = e - EE; }
    else return;
    int slot = atomicAdd(&cursor[c], 1);
    if (slot >= 0 && slot < TOT) {
        pairs[slot] = make_int2(r, __float_as_int(dinv[r] * dinv[c]));
    }
}

// batch is sorted -> group bounds are run boundaries; plain stores, no atomics.
__global__ void bounds_kernel(const int* __restrict__ batch, int* gstart, int* gend) {
    int i = blockIdx.x * blockDim.x + threadIdx.x;
    if (i >= NN) return;
    int b = batch[i];
    if (i == 0) {
        gstart[b] = 0;
    } else {
        int bp = batch[i - 1];
        if (b != bp) {
            gstart[b] = i;
            gend[bp] = i;
        }
    }
    if (i == NN - 1) gend[b] = NN;
}

// cast+transpose W (fp32 row-major [k][n]) -> Wt bf16 [n][k]
__global__ void wprep_kernel(const float* __restrict__ W, unsigned short* __restrict__ Wt) {
    int i = blockIdx.x * 256 + threadIdx.x;
    if (i < HH * HH) {
        int k = i >> 7, n = i & 127;
        Wt[n * HH + k] = f2bf(W[i]);
    }
}

// cast x fp32 -> Xbf (packed 2 bf16 per uint; low = even col)
__global__ void cast_kernel(const float* __restrict__ x, unsigned* __restrict__ Xbf) {
    int i = blockIdx.x * blockDim.x + threadIdx.x;   // uint index
    if (i >= NN * 64) return;
    float2 v = ((const float2*)x)[i];
    Xbf[i] = (unsigned)f2bf(v.x) | ((unsigned)f2bf(v.y) << 16);
}

// ---------------- per-layer kernels ----------------

// one wave per destination node; neighbor (src,w) lane-preloaded, shfl-broadcast.
// bf16 gather (256 B/row), fp32 accumulate, bf16 output (feeds MFMA gemm).
__global__ __launch_bounds__(256) void agg_kernel(const unsigned* __restrict__ Xbf,
                                                  const int* __restrict__ col_start,
                                                  const int2* __restrict__ pairs,
                                                  unsigned short* __restrict__ Abf) {
    int wid = (int)((blockIdx.x * blockDim.x + threadIdx.x) >> 6);
    int lane = threadIdx.x & 63;
    if (wid >= NN) return;
    int s0 = col_start[wid], s1 = col_start[wid + 1];
    float2 acc = make_float2(0.f, 0.f);
    for (int base = s0; base < s1; base += 64) {
        int cnt = min(64, s1 - base);
        int2 p = make_int2(0, 0);
        if (lane < cnt) p = pairs[base + lane];
        for (int j = 0; j < cnt; ++j) {
            int src = __shfl(p.x, j);
            float w = __shfl(__int_as_float(p.y), j);
            unsigned u = Xbf[(size_t)src * 64 + lane];
            acc.x += w * __uint_as_float(u << 16);
            acc.y += w * __uint_as_float(u & 0xFFFF0000u);
        }
    }
    unsigned pk = (unsigned)f2bf(acc.x) | ((unsigned)f2bf(acc.y) << 16);
    ((unsigned*)Abf)[(size_t)wid * 64 + lane] = pk;
}

__global__ void zero_stats_kernel(float* gsum, float* gsq) {
    int t = threadIdx.x;
    if (t < HH) { gsum[t] = 0.f; gsq[t] = 0.f; }
}

// H = Abf @ W + b via bf16 MFMA 16x16x32; fused column sum/sumsq for BN.
__global__ __launch_bounds__(256) void gemm_kernel(const unsigned short* __restrict__ Abf,
                                                   const unsigned short* __restrict__ Wt,
                                                   const float* __restrict__ bias,
                                                   float* __restrict__ H,
                                                   float* __restrict__ gsum,
                                                   float* __restrict__ gsq) {
    __shared__ unsigned short wlds[128 * 136];   // row stride 136 bf16 = 272B: no b128 conflicts
    __shared__ float ssum[HH], ssq[HH];
    int tid = threadIdx.x;
    if (tid < HH) { ssum[tid] = 0.f; ssq[tid] = 0.f; }
#pragma unroll
    for (int it = 0; it < 16; ++it) {            // stage 32KB Wt, coalesced, conflict-free
        int idx = it * 256 + tid;
        int r = idx >> 5, c = idx & 31;
        *(uint2*)&wlds[r * 136 + c * 4] = *(const uint2*)(Wt + r * HH + c * 4);
    }
    __syncthreads();

    int lane = tid & 63;
    int wave = tid >> 6;
    int mcol = lane & 15;
    int quad = lane >> 4;
    int rowbase = blockIdx.x * 128 + wave * 32;
    int row0 = rowbase + mcol;
    int row1 = row0 + 16;

    f32x4 acc[2][8];
#pragma unroll
    for (int mt = 0; mt < 2; ++mt)
#pragma unroll
        for (int nt = 0; nt < 8; ++nt) acc[mt][nt] = (f32x4){0.f, 0.f, 0.f, 0.f};

    s16x8 zf = {0, 0, 0, 0, 0, 0, 0, 0};
#pragma unroll
    for (int ks = 0; ks < 4; ++ks) {
        int k0 = ks * 32 + quad * 8;
        s16x8 a0 = (row0 < NN) ? *(const s16x8*)(Abf + (size_t)row0 * HH + k0) : zf;
        s16x8 a1 = (row1 < NN) ? *(const s16x8*)(Abf + (size_t)row1 * HH + k0) : zf;
#pragma unroll
        for (int nt = 0; nt < 8; ++nt) {
            s16x8 b = *(const s16x8*)&wlds[(nt * 16 + mcol) * 136 + k0];
            acc[0][nt] = __builtin_amdgcn_mfma_f32_16x16x32_bf16(a0, b, acc[0][nt], 0, 0, 0);
            acc[1][nt] = __builtin_amdgcn_mfma_f32_16x16x32_bf16(a1, b, acc[1][nt], 0, 0, 0);
        }
    }

    // epilogue: bias add, store, per-col stats (C/D: col=lane&15, row=quad*4+reg)
    float s[8], sq[8];
#pragma unroll
    for (int nt = 0; nt < 8; ++nt) { s[nt] = 0.f; sq[nt] = 0.f; }
#pragma unroll
    for (int mt = 0; mt < 2; ++mt) {
        int rbase = rowbase + mt * 16 + quad * 4;
#pragma unroll
        for (int nt = 0; nt < 8; ++nt) {
            int col = nt * 16 + mcol;
            float bv = bias[col];
            f32x4 a = acc[mt][nt];
#pragma unroll
            for (int reg = 0; reg < 4; ++reg) {
                int r = rbase + reg;
                if (r < NN) {
                    float h = a[reg] + bv;
                    H[(size_t)r * HH + col] = h;
                    s[nt] += h; sq[nt] += h * h;
                }
            }
        }
    }
#pragma unroll
    for (int nt = 0; nt < 8; ++nt) {
        float v = s[nt];  v += __shfl_xor(v, 16);  v += __shfl_xor(v, 32);
        float w = sq[nt]; w += __shfl_xor(w, 16);  w += __shfl_xor(w, 32);
        if (quad == 0) {
            atomicAdd(&ssum[nt * 16 + mcol], v);
            atomicAdd(&ssq[nt * 16 + mcol], w);
        }
    }
    __syncthreads();
    if (tid < HH) {
        atomicAdd(&gsum[tid], ssum[tid]);
        atomicAdd(&gsq[tid], ssq[tid]);
    }
}

__global__ void finalize_kernel(const float* __restrict__ gsum, const float* __restrict__ gsq,
                                const float* __restrict__ g, const float* __restrict__ beta,
                                float* __restrict__ ascale, float* __restrict__ bshift) {
    int t = threadIdx.x;
    if (t >= HH) return;
    float mu = gsum[t] / (float)NN;
    float var = gsq[t] / (float)NN - mu * mu;
    var = fmaxf(var, 0.f);
    float inv = rsqrtf(var + 1e-5f);
    float a = g[t] * inv;
    ascale[t] = a;
    bshift[t] = beta[t] - mu * a;
}

// BN affine + ReLU over H (fp32) -> Xbf (bf16, feeds next agg / pool)
__global__ void apply_kernel(const float* __restrict__ H, const float* __restrict__ ascale,
                             const float* __restrict__ bshift, unsigned* __restrict__ Xbf) {
    int i = blockIdx.x * blockDim.x + threadIdx.x;   // float4 index
    if (i >= NN * (HH / 4)) return;
    int c4 = (i & 31) * 4;
    float4 h = ((const float4*)H)[i];
    float4 a = *(const float4*)(ascale + c4);
    float4 b = *(const float4*)(bshift + c4);
    float o0 = fmaxf(a.x * h.x + b.x, 0.f);
    float o1 = fmaxf(a.y * h.y + b.y, 0.f);
    float o2 = fmaxf(a.z * h.z + b.z, 0.f);
    float o3 = fmaxf(a.w * h.w + b.w, 0.f);
    uint2 o;
    o.x = (unsigned)f2bf(o0) | ((unsigned)f2bf(o1) << 16);
    o.y = (unsigned)f2bf(o2) | ((unsigned)f2bf(o3) << 16);
    ((uint2*)Xbf)[i] = o;
}

// ---------------- pooling + fc ----------------

__global__ void pool_kernel(const unsigned* __restrict__ Xbf, const int* __restrict__ gstart,
                            const int* __restrict__ gend, float* __restrict__ poolsum) {
    int g = blockIdx.x;
    int sp = blockIdx.y;
    int t = threadIdx.x;           // 64: each handles 2 cols
    int s = gstart[g], e = gend[g];
    if (e <= s) return;
    int len = e - s;
    int chunk = (len + PSPLIT - 1) / PSPLIT;
    int cs = s + sp * chunk;
    int ce = min(cs + chunk, e);
    if (cs >= ce) return;
    float2 acc = make_float2(0.f, 0.f);
    for (int i = cs; i < ce; ++i) {
        unsigned u = Xbf[(size_t)i * 64 + t];
        acc.x += __uint_as_float(u << 16);
        acc.y += __uint_as_float(u & 0xFFFF0000u);
    }
    atomicAdd(&poolsum[g * HH + 2 * t], acc.x);
    atomicAdd(&poolsum[g * HH + 2 * t + 1], acc.y);
}

__global__ void fc_kernel(const float* __restrict__ poolsum, const int* __restrict__ gstart,
                          const int* __restrict__ gend, const float* __restrict__ fc_w,
                          const float* __restrict__ fc_b, float* __restrict__ out) {
    int g = blockIdx.x;
    int o = threadIdx.x;
    int cnt = gend[g] - gstart[g];
    float inv = (cnt > 0) ? (1.f / (float)cnt) : 0.f;
    float acc = fc_b[o];
    for (int k = 0; k < HH; ++k) acc += (poolsum[g * HH + k] * inv) * fc_w[k * HH + o];
    out[g * HH + o] = acc;
}

// ---------------- launch ----------------

extern "C" void kernel_launch(void* const* d_in, const int* in_sizes, int n_in,
                              void* d_out, int out_size, void* d_ws, size_t ws_size,
                              hipStream_t stream) {
    const float* x     = (const float*)d_in[0];
    const int*   ei    = (const int*)d_in[1];
    const int*   batch = (const int*)d_in[2];
    const float* Wl[3]    = {(const float*)d_in[3], (const float*)d_in[7], (const float*)d_in[11]};
    const float* bl[3]    = {(const float*)d_in[4], (const float*)d_in[8], (const float*)d_in[12]};
    const float* gl[3]    = {(const float*)d_in[5], (const float*)d_in[9], (const float*)d_in[13]};
    const float* betal[3] = {(const float*)d_in[6], (const float*)d_in[10], (const float*)d_in[14]};
    const float* fc_w = (const float*)d_in[15];
    const float* fc_b = (const float*)d_in[16];
    float* out = (float*)d_out;

    char* ws = (char*)d_ws;
    size_t off = 0;
    auto take = [&](size_t n) -> void* {
        void* p = ws + off;
        off = (off + n + 255) & ~(size_t)255;
        return p;
    };
    int*   deg       = (int*)take((size_t)NN * 4);
    int*   col_start = (int*)take((size_t)(NN + 1) * 4);
    int*   cursor    = (int*)take((size_t)NN * 4);
    float* dinv      = (float*)take((size_t)NN * 4);
    int2*  pairs     = (int2*)take((size_t)TOT * 8);
    int*   bsums     = (int*)take(512 * 4);
    float* gsum      = (float*)take(HH * 4);
    float* gsq       = (float*)take(HH * 4);
    float* ascale    = (float*)take(HH * 4);
    float* bshift    = (float*)take(HH * 4);
    int*   gstart    = (int*)take(GG * 4);
    int*   gend      = (int*)take(GG * 4);
    float* poolsum   = (float*)take((size_t)GG * HH * 4);
    unsigned short* wt = (unsigned short*)take((size_t)3 * HH * HH * 2);
    unsigned* Xbf    = (unsigned*)take((size_t)NN * 64 * 4);
    unsigned short* Abf = (unsigned short*)take((size_t)NN * HH * 2);
    float* Hbuf      = (float*)take((size_t)NN * HH * 4);

    const int nbScan = (NN + 255) / 256;   // 391

    init_kernel<<<(NN + 255) / 256, 256, 0, stream>>>(deg, gstart, gend, poolsum);
    count_kernel<<<(EE + 255) / 256, 256, 0, stream>>>(ei, deg);
    dinv_kernel<<<(NN + 255) / 256, 256, 0, stream>>>(deg, dinv);
    scan1_kernel<<<nbScan, 256, 0, stream>>>(deg, col_start, bsums);
    scan2_kernel<<<1, 512, 0, stream>>>(bsums, nbScan);
    scan3_kernel<<<(NN + 256) / 256, 256, 0, stream>>>(col_start, bsums, cursor);
    fill_kernel<<<(TOT + 255) / 256, 256, 0, stream>>>(ei, dinv, cursor, pairs);
    bounds_kernel<<<(NN + 255) / 256, 256, 0, stream>>>(batch, gstart, gend);
    for (int l = 0; l < 3; ++l)
        wprep_kernel<<<(HH * HH + 255) / 256, 256, 0, stream>>>(Wl[l], wt + (size_t)l * HH * HH);
    cast_kernel<<<(NN * 64 + 255) / 256, 256, 0, stream>>>(x, Xbf);

    for (int l = 0; l < 3; ++l) {
        zero_stats_kernel<<<1, 128, 0, stream>>>(gsum, gsq);
        agg_kernel<<<(NN * 64 + 255) / 256, 256, 0, stream>>>(Xbf, col_start, pairs, Abf);
        gemm_kernel<<<(NN + 127) / 128, 256, 0, stream>>>(Abf, wt + (size_t)l * HH * HH, bl[l],
                                                          Hbuf, gsum, gsq);
        finalize_kernel<<<1, 128, 0, stream>>>(gsum, gsq, gl[l], betal[l], ascale, bshift);
        apply_kernel<<<(NN * (HH / 4) + 255) / 256, 256, 0, stream>>>(Hbuf, ascale, bshift, Xbf);
    }

    pool_kernel<<<dim3(GG, PSPLIT), 64, 0, stream>>>(Xbf, gstart, gend, poolsum);
    fc_kernel<<<GG, 128, 0, stream>>>(poolsum, gstart, gend, fc_w, fc_b, out);
}

// Round 6
// 727.721 us; speedup vs baseline: 2.7550x; 1.1796x over previous
//
#include <hip/hip_runtime.h>

#define NN 100000
#define EE 1600000
#define HH 128
#define GG 64
#define TOT (EE + NN)
#define PSPLIT 8

typedef __attribute__((ext_vector_type(8))) short s16x8;
typedef __attribute__((ext_vector_type(4))) float f32x4;

__device__ __forceinline__ unsigned short f2bf(float f) {
    unsigned u = __float_as_uint(f);
    u = u + 0x7FFFu + ((u >> 16) & 1u);   // round-to-nearest-even
    return (unsigned short)(u >> 16);
}

// ---------------- graph prep ----------------

__global__ void init_kernel(int* deg, int* gstart, int* gend, float* poolsum) {
    int i = blockIdx.x * blockDim.x + threadIdx.x;
    if (i < NN) deg[i] = 1;               // self-loop
    if (i < GG) { gstart[i] = NN; gend[i] = 0; }
    if (i < GG * HH) poolsum[i] = 0.f;
}

__global__ void count_kernel(const int* __restrict__ ei, int* deg) {
    int e = blockIdx.x * blockDim.x + threadIdx.x;
    if (e < EE) {
        int c = ei[EE + e];
        if (c >= 0 && c < NN) atomicAdd(&deg[c], 1);   // col = target
    }
}

__global__ void dinv_kernel(const int* __restrict__ deg, float* __restrict__ dinv) {
    int i = blockIdx.x * blockDim.x + threadIdx.x;
    if (i < NN) dinv[i] = rsqrtf((float)deg[i]);  // deg >= 1 always
}

// exclusive scan of deg -> col_start (3 phases)
__global__ void scan1_kernel(const int* __restrict__ deg, int* __restrict__ out, int* __restrict__ bsums) {
    __shared__ int sh[256];
    int x = threadIdx.x;
    int i = blockIdx.x * 256 + x;
    int v = (i < NN) ? deg[i] : 0;
    sh[x] = v;
    __syncthreads();
    for (int off = 1; off < 256; off <<= 1) {
        int t = (x >= off) ? sh[x - off] : 0;
        __syncthreads();
        sh[x] += t;
        __syncthreads();
    }
    if (i < NN) out[i] = sh[x] - v;     // block-local exclusive
    if (x == 255) bsums[blockIdx.x] = sh[255];
}

__global__ void scan2_kernel(int* __restrict__ bsums, int nb) {
    __shared__ int sh[512];
    int x = threadIdx.x;
    int v = (x < nb) ? bsums[x] : 0;
    sh[x] = v;
    __syncthreads();
    for (int off = 1; off < 512; off <<= 1) {
        int t = (x >= off) ? sh[x - off] : 0;
        __syncthreads();
        sh[x] += t;
        __syncthreads();
    }
    if (x < nb) bsums[x] = sh[x] - v;   // exclusive
}

__global__ void scan3_kernel(int* __restrict__ col_start, const int* __restrict__ bsums, int* __restrict__ cursor) {
    int i = blockIdx.x * blockDim.x + threadIdx.x;
    if (i < NN) {
        int v = col_start[i] + bsums[i >> 8];
        col_start[i] = v;
        cursor[i] = v;
    } else if (i == NN) {
        col_start[NN] = TOT;
    }
}

// scatter only the 4B source id (wnorm recomputed in agg): halves random write-line traffic
__global__ void fill_kernel(const int* __restrict__ ei, int* cursor, int* __restrict__ srcv) {
    int e = blockIdx.x * blockDim.x + threadIdx.x;
    int r, c;
    if (e < EE) { r = ei[e]; c = ei[EE + e]; }
    else if (e < TOT) { r = c = e - EE; }
    else return;
    int slot = atomicAdd(&cursor[c], 1);
    if (slot >= 0 && slot < TOT) srcv[slot] = r;
}

// batch is sorted -> group bounds are run boundaries; plain stores, no atomics.
__global__ void bounds_kernel(const int* __restrict__ batch, int* gstart, int* gend) {
    int i = blockIdx.x * blockDim.x + threadIdx.x;
    if (i >= NN) return;
    int b = batch[i];
    if (i == 0) {
        gstart[b] = 0;
    } else {
        int bp = batch[i - 1];
        if (b != bp) {
            gstart[b] = i;
            gend[bp] = i;
        }
    }
    if (i == NN - 1) gend[b] = NN;
}

// cast+transpose all 3 W (fp32 [k][n]) -> Wt bf16 [n][k], one launch
__global__ void wprep_kernel(const float* __restrict__ W0, const float* __restrict__ W1,
                             const float* __restrict__ W2, unsigned short* __restrict__ Wt) {
    int i = blockIdx.x * 256 + threadIdx.x;
    int l = i >> 14;                      // HH*HH = 16384 per layer
    int r = i & 16383;
    if (l < 3) {
        const float* W = (l == 0) ? W0 : (l == 1) ? W1 : W2;
        int k = r >> 7, n = r & 127;
        Wt[l * HH * HH + n * HH + k] = f2bf(W[r]);
    }
}

// cast x fp32 -> Xbf (packed 2 bf16 per uint; low = even col)
__global__ void cast_kernel(const float* __restrict__ x, unsigned* __restrict__ Xbf) {
    int i = blockIdx.x * blockDim.x + threadIdx.x;   // uint index
    if (i >= NN * 64) return;
    float2 v = ((const float2*)x)[i];
    Xbf[i] = (unsigned)f2bf(v.x) | ((unsigned)f2bf(v.y) << 16);
}

// ---------------- per-layer kernels ----------------

// one wave per destination node; neighbor src lane-preloaded (w computed from dinv),
// 8-way unrolled gather for ILP; fp32 accumulate; bf16 output. Block 0 zeroes BN stats.
__global__ __launch_bounds__(256) void agg_kernel(const unsigned* __restrict__ Xbf,
                                                  const int* __restrict__ col_start,
                                                  const int* __restrict__ srcv,
                                                  const float* __restrict__ dinv,
                                                  unsigned short* __restrict__ Abf,
                                                  float* __restrict__ gsum,
                                                  float* __restrict__ gsq) {
    if (blockIdx.x == 0 && threadIdx.x < HH) {
        gsum[threadIdx.x] = 0.f;
        gsq[threadIdx.x] = 0.f;
    }
    int wid = (int)((blockIdx.x * blockDim.x + threadIdx.x) >> 6);
    int lane = threadIdx.x & 63;
    if (wid >= NN) return;
    int s0 = col_start[wid], s1 = col_start[wid + 1];
    float dd = dinv[wid];
    float2 acc = make_float2(0.f, 0.f);
    for (int base = s0; base < s1; base += 64) {
        int cnt = min(64, s1 - base);
        int msrc = 0;
        float mw = 0.f;
        if (lane < cnt) { msrc = srcv[base + lane]; mw = dinv[msrc] * dd; }
        int j = 0;
        for (; j + 8 <= cnt; j += 8) {
            unsigned u[8];
            float w[8];
#pragma unroll
            for (int k = 0; k < 8; ++k) {
                int src = __shfl(msrc, j + k);
                w[k] = __shfl(mw, j + k);
                u[k] = Xbf[(size_t)src * 64 + lane];
            }
#pragma unroll
            for (int k = 0; k < 8; ++k) {
                acc.x += w[k] * __uint_as_float(u[k] << 16);
                acc.y += w[k] * __uint_as_float(u[k] & 0xFFFF0000u);
            }
        }
        for (; j < cnt; ++j) {
            int src = __shfl(msrc, j);
            float w = __shfl(mw, j);
            unsigned u = Xbf[(size_t)src * 64 + lane];
            acc.x += w * __uint_as_float(u << 16);
            acc.y += w * __uint_as_float(u & 0xFFFF0000u);
        }
    }
    unsigned pk = (unsigned)f2bf(acc.x) | ((unsigned)f2bf(acc.y) << 16);
    ((unsigned*)Abf)[(size_t)wid * 64 + lane] = pk;
}

// pass 1: MFMA product, BN column sum/sumsq only — H never materialized.
__global__ __launch_bounds__(256) void gemm_stats_kernel(const unsigned short* __restrict__ Abf,
                                                         const unsigned short* __restrict__ Wt,
                                                         const float* __restrict__ bias,
                                                         float* __restrict__ gsum,
                                                         float* __restrict__ gsq) {
    __shared__ unsigned short wlds[128 * 136];   // row stride 136 bf16 = 272B: no b128 conflicts
    __shared__ float ssum[HH], ssq[HH];
    int tid = threadIdx.x;
    if (tid < HH) { ssum[tid] = 0.f; ssq[tid] = 0.f; }
#pragma unroll
    for (int it = 0; it < 16; ++it) {
        int idx = it * 256 + tid;
        int r = idx >> 5, c = idx & 31;
        *(uint2*)&wlds[r * 136 + c * 4] = *(const uint2*)(Wt + r * HH + c * 4);
    }
    __syncthreads();

    int lane = tid & 63;
    int wave = tid >> 6;
    int mcol = lane & 15;
    int quad = lane >> 4;
    int rowbase = blockIdx.x * 128 + wave * 32;
    int row0 = rowbase + mcol;
    int row1 = row0 + 16;

    f32x4 acc[2][8];
#pragma unroll
    for (int mt = 0; mt < 2; ++mt)
#pragma unroll
        for (int nt = 0; nt < 8; ++nt) acc[mt][nt] = (f32x4){0.f, 0.f, 0.f, 0.f};

    s16x8 zf = {0, 0, 0, 0, 0, 0, 0, 0};
#pragma unroll
    for (int ks = 0; ks < 4; ++ks) {
        int k0 = ks * 32 + quad * 8;
        s16x8 a0 = (row0 < NN) ? *(const s16x8*)(Abf + (size_t)row0 * HH + k0) : zf;
        s16x8 a1 = (row1 < NN) ? *(const s16x8*)(Abf + (size_t)row1 * HH + k0) : zf;
#pragma unroll
        for (int nt = 0; nt < 8; ++nt) {
            s16x8 b = *(const s16x8*)&wlds[(nt * 16 + mcol) * 136 + k0];
            acc[0][nt] = __builtin_amdgcn_mfma_f32_16x16x32_bf16(a0, b, acc[0][nt], 0, 0, 0);
            acc[1][nt] = __builtin_amdgcn_mfma_f32_16x16x32_bf16(a1, b, acc[1][nt], 0, 0, 0);
        }
    }

    float s[8], sq[8];
#pragma unroll
    for (int nt = 0; nt < 8; ++nt) { s[nt] = 0.f; sq[nt] = 0.f; }
#pragma unroll
    for (int mt = 0; mt < 2; ++mt) {
        int rbase = rowbase + mt * 16 + quad * 4;
#pragma unroll
        for (int nt = 0; nt < 8; ++nt) {
            float bv = bias[nt * 16 + mcol];
            f32x4 a = acc[mt][nt];
#pragma unroll
            for (int reg = 0; reg < 4; ++reg) {
                if (rbase + reg < NN) {
                    float h = a[reg] + bv;
                    s[nt] += h; sq[nt] += h * h;
                }
            }
        }
    }
#pragma unroll
    for (int nt = 0; nt < 8; ++nt) {
        float v = s[nt];  v += __shfl_xor(v, 16);  v += __shfl_xor(v, 32);
        float w = sq[nt]; w += __shfl_xor(w, 16);  w += __shfl_xor(w, 32);
        if (quad == 0) {
            atomicAdd(&ssum[nt * 16 + mcol], v);
            atomicAdd(&ssq[nt * 16 + mcol], w);
        }
    }
    __syncthreads();
    if (tid < HH) {
        atomicAdd(&gsum[tid], ssum[tid]);
        atomicAdd(&gsq[tid], ssq[tid]);
    }
}

// pass 2: recompute the identical MFMA product, apply bias+BN+ReLU, store bf16 X.
__global__ __launch_bounds__(256) void gemm_apply_kernel(const unsigned short* __restrict__ Abf,
                                                         const unsigned short* __restrict__ Wt,
                                                         const float* __restrict__ bias,
                                                         const float* __restrict__ gsum,
                                                         const float* __restrict__ gsq,
                                                         const float* __restrict__ g,
                                                         const float* __restrict__ beta,
                                                         unsigned short* __restrict__ Xb16) {
    __shared__ unsigned short wlds[128 * 136];
    __shared__ float asc[HH], bsh[HH];
    int tid = threadIdx.x;
#pragma unroll
    for (int it = 0; it < 16; ++it) {
        int idx = it * 256 + tid;
        int r = idx >> 5, c = idx & 31;
        *(uint2*)&wlds[r * 136 + c * 4] = *(const uint2*)(Wt + r * HH + c * 4);
    }
    if (tid < HH) {
        float mu = gsum[tid] * (1.f / (float)NN);
        float var = fmaxf(gsq[tid] * (1.f / (float)NN) - mu * mu, 0.f);
        float a = g[tid] * rsqrtf(var + 1e-5f);
        asc[tid] = a;
        bsh[tid] = a * (bias[tid] - mu) + beta[tid];   // o = a*acc + bsh
    }
    __syncthreads();

    int lane = tid & 63;
    int wave = tid >> 6;
    int mcol = lane & 15;
    int quad = lane >> 4;
    int rowbase = blockIdx.x * 128 + wave * 32;
    int row0 = rowbase + mcol;
    int row1 = row0 + 16;

    f32x4 acc[2][8];
#pragma unroll
    for (int mt = 0; mt < 2; ++mt)
#pragma unroll
        for (int nt = 0; nt < 8; ++nt) acc[mt][nt] = (f32x4){0.f, 0.f, 0.f, 0.f};

    s16x8 zf = {0, 0, 0, 0, 0, 0, 0, 0};
#pragma unroll
    for (int ks = 0; ks < 4; ++ks) {
        int k0 = ks * 32 + quad * 8;
        s16x8 a0 = (row0 < NN) ? *(const s16x8*)(Abf + (size_t)row0 * HH + k0) : zf;
        s16x8 a1 = (row1 < NN) ? *(const s16x8*)(Abf + (size_t)row1 * HH + k0) : zf;
#pragma unroll
        for (int nt = 0; nt < 8; ++nt) {
            s16x8 b = *(const s16x8*)&wlds[(nt * 16 + mcol) * 136 + k0];
            acc[0][nt] = __builtin_amdgcn_mfma_f32_16x16x32_bf16(a0, b, acc[0][nt], 0, 0, 0);
            acc[1][nt] = __builtin_amdgcn_mfma_f32_16x16x32_bf16(a1, b, acc[1][nt], 0, 0, 0);
        }
    }

#pragma unroll
    for (int mt = 0; mt < 2; ++mt) {
        int rbase = rowbase + mt * 16 + quad * 4;
#pragma unroll
        for (int nt = 0; nt < 8; ++nt) {
            int col = nt * 16 + mcol;
            float av = asc[col], bv = bsh[col];
            f32x4 a = acc[mt][nt];
#pragma unroll
            for (int reg = 0; reg < 4; ++reg) {
                int r = rbase + reg;
                if (r < NN) {
                    float o = fmaxf(av * a[reg] + bv, 0.f);
                    Xb16[(size_t)r * HH + col] = f2bf(o);
                }
            }
        }
    }
}

// ---------------- pooling + fc ----------------

__global__ void pool_kernel(const unsigned* __restrict__ Xbf, const int* __restrict__ gstart,
                            const int* __restrict__ gend, float* __restrict__ poolsum) {
    int g = blockIdx.x;
    int sp = blockIdx.y;
    int t = threadIdx.x;           // 64: each handles 2 cols
    int s = gstart[g], e = gend[g];
    if (e <= s) return;
    int len = e - s;
    int chunk = (len + PSPLIT - 1) / PSPLIT;
    int cs = s + sp * chunk;
    int ce = min(cs + chunk, e);
    if (cs >= ce) return;
    float2 acc = make_float2(0.f, 0.f);
    for (int i = cs; i < ce; ++i) {
        unsigned u = Xbf[(size_t)i * 64 + t];
        acc.x += __uint_as_float(u << 16);
        acc.y += __uint_as_float(u & 0xFFFF0000u);
    }
    atomicAdd(&poolsum[g * HH + 2 * t], acc.x);
    atomicAdd(&poolsum[g * HH + 2 * t + 1], acc.y);
}

__global__ void fc_kernel(const float* __restrict__ poolsum, const int* __restrict__ gstart,
                          const int* __restrict__ gend, const float* __restrict__ fc_w,
                          const float* __restrict__ fc_b, float* __restrict__ out) {
    int g = blockIdx.x;
    int o = threadIdx.x;
    int cnt = gend[g] - gstart[g];
    float inv = (cnt > 0) ? (1.f / (float)cnt) : 0.f;
    float acc = fc_b[o];
    for (int k = 0; k < HH; ++k) acc += (poolsum[g * HH + k] * inv) * fc_w[k * HH + o];
    out[g * HH + o] = acc;
}

// ---------------- launch ----------------

extern "C" void kernel_launch(void* const* d_in, const int* in_sizes, int n_in,
                              void* d_out, int out_size, void* d_ws, size_t ws_size,
                              hipStream_t stream) {
    const float* x     = (const float*)d_in[0];
    const int*   ei    = (const int*)d_in[1];
    const int*   batch = (const int*)d_in[2];
    const float* Wl[3]    = {(const float*)d_in[3], (const float*)d_in[7], (const float*)d_in[11]};
    const float* bl[3]    = {(const float*)d_in[4], (const float*)d_in[8], (const float*)d_in[12]};
    const float* gl[3]    = {(const float*)d_in[5], (const float*)d_in[9], (const float*)d_in[13]};
    const float* betal[3] = {(const float*)d_in[6], (const float*)d_in[10], (const float*)d_in[14]};
    const float* fc_w = (const float*)d_in[15];
    const float* fc_b = (const float*)d_in[16];
    float* out = (float*)d_out;

    char* ws = (char*)d_ws;
    size_t off = 0;
    auto take = [&](size_t n) -> void* {
        void* p = ws + off;
        off = (off + n + 255) & ~(size_t)255;
        return p;
    };
    int*   deg       = (int*)take((size_t)NN * 4);
    int*   col_start = (int*)take((size_t)(NN + 1) * 4);
    int*   cursor    = (int*)take((size_t)NN * 4);
    float* dinv      = (float*)take((size_t)NN * 4);
    int*   srcv      = (int*)take((size_t)TOT * 4);
    int*   bsums     = (int*)take(512 * 4);
    float* gsum      = (float*)take(HH * 4);
    float* gsq       = (float*)take(HH * 4);
    int*   gstart    = (int*)take(GG * 4);
    int*   gend      = (int*)take(GG * 4);
    float* poolsum   = (float*)take((size_t)GG * HH * 4);
    unsigned short* wt = (unsigned short*)take((size_t)3 * HH * HH * 2);
    unsigned* Xbf    = (unsigned*)take((size_t)NN * 64 * 4);
    unsigned short* Abf = (unsigned short*)take((size_t)NN * HH * 2);

    const int nbScan = (NN + 255) / 256;   // 391

    init_kernel<<<(NN + 255) / 256, 256, 0, stream>>>(deg, gstart, gend, poolsum);
    count_kernel<<<(EE + 255) / 256, 256, 0, stream>>>(ei, deg);
    dinv_kernel<<<(NN + 255) / 256, 256, 0, stream>>>(deg, dinv);
    scan1_kernel<<<nbScan, 256, 0, stream>>>(deg, col_start, bsums);
    scan2_kernel<<<1, 512, 0, stream>>>(bsums, nbScan);
    scan3_kernel<<<(NN + 256) / 256, 256, 0, stream>>>(col_start, bsums, cursor);
    fill_kernel<<<(TOT + 255) / 256, 256, 0, stream>>>(ei, cursor, srcv);
    bounds_kernel<<<(NN + 255) / 256, 256, 0, stream>>>(batch, gstart, gend);
    wprep_kernel<<<(3 * HH * HH + 255) / 256, 256, 0, stream>>>(Wl[0], Wl[1], Wl[2], wt);
    cast_kernel<<<(NN * 64 + 255) / 256, 256, 0, stream>>>(x, Xbf);

    for (int l = 0; l < 3; ++l) {
        const unsigned short* W = wt + (size_t)l * HH * HH;
        agg_kernel<<<(NN * 64 + 255) / 256, 256, 0, stream>>>(Xbf, col_start, srcv, dinv,
                                                              Abf, gsum, gsq);
        gemm_stats_kernel<<<(NN + 127) / 128, 256, 0, stream>>>(Abf, W, bl[l], gsum, gsq);
        gemm_apply_kernel<<<(NN + 127) / 128, 256, 0, stream>>>(Abf, W, bl[l], gsum, gsq,
                                                                gl[l], betal[l],
                                                                (unsigned short*)Xbf);
    }

    pool_kernel<<<dim3(GG, PSPLIT), 64, 0, stream>>>(Xbf, gstart, gend, poolsum);
    fc_kernel<<<GG, 128, 0, stream>>>(poolsum, gstart, gend, fc_w, fc_b, out);
}